// Round 4
// baseline (292.973 us; speedup 1.0000x reference)
//
#include <hip/hip_runtime.h>

// ---------------- problem constants ----------------
#define G_DIM 3072
#define P_DIM 1024
#define ALPHA 0.1f

typedef __attribute__((ext_vector_type(8))) __bf16 bf16x8;
typedef __attribute__((ext_vector_type(4))) float  f32x4;

// workspace layout (bytes), peak 69.2 MB
#define GG2      ((size_t)G_DIM * G_DIM * 2)          // bf16 G×G = 18,874,368 B
#define S_OFF    ((size_t)0)
#define ST_OFF   (GG2)
#define X_OFF    ((size_t)0)
#define XBYTES   ((size_t)8192 * G_DIM * 2)           // 50,331,648 B
#define W_OFF    (XBYTES)

// ---------------- softmax: S = alpha * softmax(scores, -inf diag) ----------------
__global__ __launch_bounds__(256) void row_softmax_k(const float* __restrict__ gg,
                                                     __bf16* __restrict__ S) {
  const int i = blockIdx.x;
  const float* row = gg + (size_t)i * G_DIM * 2;  // [G][2], channel 1
  const int tid = threadIdx.x;
  const int lane = tid & 63, wave = tid >> 6;

  float v[12];
  float m = -INFINITY;
#pragma unroll
  for (int t = 0; t < 12; ++t) {
    int j = tid + t * 256;
    float x = row[2 * j + 1];
    if (j == i) x = -INFINITY;
    v[t] = x;
    m = fmaxf(m, x);
  }
#pragma unroll
  for (int o = 32; o; o >>= 1) m = fmaxf(m, __shfl_xor(m, o));
  __shared__ float red[4];
  if (lane == 0) red[wave] = m;
  __syncthreads();
  m = fmaxf(fmaxf(red[0], red[1]), fmaxf(red[2], red[3]));

  float s = 0.f;
#pragma unroll
  for (int t = 0; t < 12; ++t) {
    v[t] = __expf(v[t] - m);
    s += v[t];
  }
#pragma unroll
  for (int o = 32; o; o >>= 1) s += __shfl_xor(s, o);
  __syncthreads();
  if (lane == 0) red[wave] = s;
  __syncthreads();
  s = red[0] + red[1] + red[2] + red[3];

  const float scale = ALPHA / s;
  __bf16* out = S + (size_t)i * G_DIM;
#pragma unroll
  for (int t = 0; t < 12; ++t) {
    int j = tid + t * 256;
    out[j] = (__bf16)(v[t] * scale);
  }
}

// ---------------- bf16 transpose ----------------
__global__ void transpose_k(const __bf16* __restrict__ in, __bf16* __restrict__ out) {
  __shared__ __bf16 t[32][33];
  const int bx = blockIdx.x * 32, by = blockIdx.y * 32;
  const int tx = threadIdx.x, ty = threadIdx.y;
#pragma unroll
  for (int k = 0; k < 32; k += 8)
    t[ty + k][tx] = in[(size_t)(by + ty + k) * G_DIM + bx + tx];
  __syncthreads();
#pragma unroll
  for (int k = 0; k < 32; k += 8)
    out[(size_t)(bx + ty + k) * G_DIM + by + tx] = t[tx][ty + k];
}

// ---------------- deinterleave channels into X [8192][G] bf16, row = rr*2 + c ------
__global__ __launch_bounds__(384) void deinterleave_k(const float* __restrict__ pg,
                                                      const float* __restrict__ gg,
                                                      __bf16* __restrict__ X) {
  const int rr = blockIdx.x;  // 0..4095
  const float* src = (rr < P_DIM) ? (pg + (size_t)rr * G_DIM * 2)
                                  : (gg + (size_t)(rr - P_DIM) * G_DIM * 2);
  const int t = threadIdx.x;
  const float4* s4 = (const float4*)(src + (size_t)t * 16);
  float4 a = s4[0], b = s4[1], c = s4[2], d = s4[3];
  bf16x8 v0, v1;
  v0[0] = (__bf16)a.x; v1[0] = (__bf16)a.y;
  v0[1] = (__bf16)a.z; v1[1] = (__bf16)a.w;
  v0[2] = (__bf16)b.x; v1[2] = (__bf16)b.y;
  v0[3] = (__bf16)b.z; v1[3] = (__bf16)b.w;
  v0[4] = (__bf16)c.x; v1[4] = (__bf16)c.y;
  v0[5] = (__bf16)c.z; v1[5] = (__bf16)c.w;
  v0[6] = (__bf16)d.x; v1[6] = (__bf16)d.y;
  v0[7] = (__bf16)d.z; v1[7] = (__bf16)d.w;
  *(bf16x8*)(X + (size_t)(rr * 2) * G_DIM + t * 8)     = v0;
  *(bf16x8*)(X + (size_t)(rr * 2 + 1) * G_DIM + t * 8) = v1;
}

// ------- one staged global->LDS chunk (1 KiB), pre-swizzled source (rule #21) -------
// chunk covers rows [chunk*8, chunk*8+8) of a [rows][64] bf16 tile (128 B rows),
// linear LDS dest; reader applies slot ^= (row&7)
__device__ __forceinline__ void stage1(const __bf16* __restrict__ src, size_t row0,
                                       int K, int k0, char* ldsbase, int chunk, int lane) {
  int Lb = chunk << 10;                   // wave-uniform LDS byte base
  int L  = Lb + lane * 16;                // this lane's dest byte
  int r  = L >> 7;                        // tile row
  int slot = ((L >> 4) & 7) ^ (r & 7);    // inverse swizzle on SOURCE
  const __bf16* g = src + (row0 + (size_t)r) * (size_t)K + (size_t)(k0 + slot * 8);
  __builtin_amdgcn_global_load_lds((const __attribute__((address_space(1))) void*)g,
                                   (__attribute__((address_space(3))) void*)(ldsbase + Lb),
                                   16, 0, 0);
}

#define MFMA16(a, b, c) __builtin_amdgcn_mfma_f32_16x16x32_bf16((a), (b), (c), 0, 0, 0)

// ---------------- ring-3 fine-interleaved NT GEMM: C[i,j] = sum_k A[i,k]*B[j,k] ------
// Tile 256x128, BK=64, 8 waves (4Mx2N), wave tile 64x64.
// LDS ring of 3 slots (A 32K + B 16K each); stage tile t+2 interleaved across the
// 4 compute phases of tile t; ONE barrier/K-tile; counted vmcnt(6) (2-tile slack).
// MODE 1: C bf16 = 0.9*(acc + e0[i,j])          (W = 0.9*(S^2 + S))
// MODE 2: d_out f32 paired = acc + 0.9*orig f32 (propagate, X row = rr*2+c)
template <int MODE>
__global__ __launch_bounds__(512, 2) void gemm_ring(const __bf16* __restrict__ A,
                                                    const __bf16* __restrict__ B,
                                                    void* __restrict__ C,
                                                    const __bf16* __restrict__ e0,
                                                    const float* __restrict__ pgin,
                                                    const float* __restrict__ ggin,
                                                    int M, int N, int K) {
  __shared__ char lds[147456];   // 3 x (32 KiB A + 16 KiB B)

  const int tid = threadIdx.x;
  const int wave = tid >> 6, lane = tid & 63;
  const int wm = wave >> 1, wn = wave & 1;   // 4M x 2N
  const int lr = lane & 15, g4 = lane >> 4;

  const size_t arow0 = (size_t)blockIdx.y * 256;
  const size_t brow0 = (size_t)blockIdx.x * 128;

  f32x4 acc[4][4] = {};
  const int NT = K / 64;

  // prologue: stage tiles 0 and 1 (6 per-wave issues each)
  {
    char* s0 = lds;
    char* s1 = lds + 49152;
#pragma unroll
    for (int q = 0; q < 4; ++q) stage1(A, arow0, K, 0, s0, wave * 4 + q, lane);
#pragma unroll
    for (int q = 0; q < 2; ++q) stage1(B, brow0, K, 0, s0 + 32768, wave * 2 + q, lane);
#pragma unroll
    for (int q = 0; q < 4; ++q) stage1(A, arow0, K, 64, s1, wave * 4 + q, lane);
#pragma unroll
    for (int q = 0; q < 2; ++q) stage1(B, brow0, K, 64, s1 + 32768, wave * 2 + q, lane);
  }

  for (int t = 0; t < NT; ++t) {
    char* As = lds + (t % 3) * 49152;
    char* Bs = As + 32768;
    char* Ad = lds + ((t + 2) % 3) * 49152;   // prefetch dest (dead slot)
    const int k2 = (t + 2) * 64;
    const bool pf = (t + 2) < NT;

    // counted wait: tile t's 6 loads done, tile t+1's 6 stay in flight (T4)
    if (t + 1 < NT) asm volatile("s_waitcnt vmcnt(6)" ::: "memory");
    else            asm volatile("s_waitcnt vmcnt(0)" ::: "memory");
    __builtin_amdgcn_s_barrier();

    const int arow = wm * 64 + lr;
    const int brow = wn * 64 + lr;
    const int x0 = ((g4) ^ (lr & 7)) * 16;        // ks0 slot byte (swizzled)
    const int x1 = ((4 + g4) ^ (lr & 7)) * 16;    // ks1

    bf16x8 av0[4], av1[4], bv0[4], bv1[4];

    // ---- phase 0: ks0, nf 0-1 ----
    if (pf) {
      stage1(A, arow0, K, k2, Ad, wave * 4 + 0, lane);
      stage1(A, arow0, K, k2, Ad, wave * 4 + 1, lane);
    }
#pragma unroll
    for (int mf = 0; mf < 4; ++mf)
      av0[mf] = *(const bf16x8*)(As + (arow + mf * 16) * 128 + x0);
    bv0[0] = *(const bf16x8*)(Bs + (brow +  0) * 128 + x0);
    bv0[1] = *(const bf16x8*)(Bs + (brow + 16) * 128 + x0);
    __builtin_amdgcn_s_setprio(1);
#pragma unroll
    for (int mf = 0; mf < 4; ++mf) {
      acc[mf][0] = MFMA16(av0[mf], bv0[0], acc[mf][0]);
      acc[mf][1] = MFMA16(av0[mf], bv0[1], acc[mf][1]);
    }
    __builtin_amdgcn_s_setprio(0);

    // ---- phase 1: ks0, nf 2-3 ----
    if (pf) {
      stage1(A, arow0, K, k2, Ad, wave * 4 + 2, lane);
      stage1(A, arow0, K, k2, Ad, wave * 4 + 3, lane);
    }
    bv0[2] = *(const bf16x8*)(Bs + (brow + 32) * 128 + x0);
    bv0[3] = *(const bf16x8*)(Bs + (brow + 48) * 128 + x0);
    __builtin_amdgcn_s_setprio(1);
#pragma unroll
    for (int mf = 0; mf < 4; ++mf) {
      acc[mf][2] = MFMA16(av0[mf], bv0[2], acc[mf][2]);
      acc[mf][3] = MFMA16(av0[mf], bv0[3], acc[mf][3]);
    }
    __builtin_amdgcn_s_setprio(0);

    // ---- phase 2: ks1, nf 2-3 ----
    if (pf) stage1(B, brow0, K, k2, Ad + 32768, wave * 2 + 0, lane);
#pragma unroll
    for (int mf = 0; mf < 4; ++mf)
      av1[mf] = *(const bf16x8*)(As + (arow + mf * 16) * 128 + x1);
    bv1[2] = *(const bf16x8*)(Bs + (brow + 32) * 128 + x1);
    bv1[3] = *(const bf16x8*)(Bs + (brow + 48) * 128 + x1);
    __builtin_amdgcn_s_setprio(1);
#pragma unroll
    for (int mf = 0; mf < 4; ++mf) {
      acc[mf][2] = MFMA16(av1[mf], bv1[2], acc[mf][2]);
      acc[mf][3] = MFMA16(av1[mf], bv1[3], acc[mf][3]);
    }
    __builtin_amdgcn_s_setprio(0);

    // ---- phase 3: ks1, nf 0-1 ----
    if (pf) stage1(B, brow0, K, k2, Ad + 32768, wave * 2 + 1, lane);
    bv1[0] = *(const bf16x8*)(Bs + (brow +  0) * 128 + x1);
    bv1[1] = *(const bf16x8*)(Bs + (brow + 16) * 128 + x1);
    __builtin_amdgcn_s_setprio(1);
#pragma unroll
    for (int mf = 0; mf < 4; ++mf) {
      acc[mf][0] = MFMA16(av1[mf], bv1[0], acc[mf][0]);
      acc[mf][1] = MFMA16(av1[mf], bv1[1], acc[mf][1]);
    }
    __builtin_amdgcn_s_setprio(0);

    // all of this tile's LDS reads complete before next top-barrier
    asm volatile("s_waitcnt lgkmcnt(0)" ::: "memory");
  }

  // epilogue — C/D layout: col = lane&15, row = (lane>>4)*4 + reg  [measured m89/m91]
  const int r0 = (int)arow0 + wm * 64;
  const int c0 = (int)brow0 + wn * 64;
#pragma unroll
  for (int mf = 0; mf < 4; ++mf) {
#pragma unroll
    for (int nf = 0; nf < 4; ++nf) {
      const int col = c0 + nf * 16 + lr;
      if constexpr (MODE == 1) {
#pragma unroll
        for (int jj = 0; jj < 4; ++jj) {
          const int row = r0 + mf * 16 + g4 * 4 + jj;
          float w = 0.9f * (acc[mf][nf][jj] + (float)e0[(size_t)row * N + col]);
          ((__bf16*)C)[(size_t)row * N + col] = (__bf16)w;
        }
      } else {
        // rows come in (even,odd) pairs = (c=0, c=1) of original row rr
#pragma unroll
        for (int jp = 0; jp < 2; ++jp) {
          const int row = r0 + mf * 16 + g4 * 4 + jp * 2;  // even
          const int rr = row >> 1;
          const size_t base = (size_t)rr * G_DIM * 2 + (size_t)col * 2;
          const float* src = (rr < P_DIM) ? (pgin + base)
                                          : (ggin + base - (size_t)P_DIM * G_DIM * 2);
          float2 sv = *(const float2*)src;
          float2 ov;
          ov.x = acc[mf][nf][jp * 2]     + 0.9f * sv.x;
          ov.y = acc[mf][nf][jp * 2 + 1] + 0.9f * sv.y;
          *(float2*)((float*)C + base) = ov;
        }
      }
    }
  }
}

// ---------------- launch ----------------
extern "C" void kernel_launch(void* const* d_in, const int* in_sizes, int n_in,
                              void* d_out, int out_size, void* d_ws, size_t ws_size,
                              hipStream_t stream) {
  const float* pg = (const float*)d_in[0];  // [P,G,2] f32
  const float* gg = (const float*)d_in[1];  // [G,G,2] f32
  float* out = (float*)d_out;

  char* ws = (char*)d_ws;
  __bf16* S  = (__bf16*)(ws + S_OFF);
  __bf16* St = (__bf16*)(ws + ST_OFF);
  __bf16* W  = (__bf16*)(ws + W_OFF);
  __bf16* X  = (__bf16*)(ws + X_OFF);    // overlays S/St (dead by then)

  // 1. S = alpha * softmax(gg[:,:,1], -inf diag)      [G,G] bf16
  row_softmax_k<<<G_DIM, 256, 0, stream>>>(gg, S);
  // 2. St = S^T
  transpose_k<<<dim3(96, 96), dim3(32, 8), 0, stream>>>(S, St);
  // 3. W = 0.9*(S*S + S)   (NT: A=S, B=St; epilogue adds S, scales)
  gemm_ring<1><<<dim3(24, 12), 512, 0, stream>>>(S, St, W, S,
                                                 nullptr, nullptr, G_DIM, G_DIM, G_DIM);
  // 4. X[rr*2+c][g] = bf16(src[rr][g][c])
  deinterleave_k<<<4096, 384, 0, stream>>>(pg, gg, X);
  // 5. out = X * W^T + 0.9 * X_f32, paired channels into d_out
  gemm_ring<2><<<dim3(24, 32), 512, 0, stream>>>(X, W, out, nullptr,
                                                 pg, gg, 8192, G_DIM, G_DIM);
  (void)in_sizes; (void)n_in; (void)out_size; (void)ws_size;
}